// Round 6
// baseline (662.886 us; speedup 1.0000x reference)
//
#include <hip/hip_runtime.h>

#define N_NODES 100000
#define N_EDGES 1600000
#define N_GRAPHS 1000
#define H 128
#define DEPTH 4
#define NB 391        // buckets of 256 nodes
#define BCAP 4864     // bucket capacity (mean 4096, sd 64 -> +12 sigma)
#define WPITCH 136    // bf16 pitch per output col (reads time-share bank quads = free)
#define WSLOT (H * WPITCH)  // 17408 shorts = 34816 B per weight matrix

typedef __attribute__((ext_vector_type(8))) short bf16x8;
typedef __attribute__((ext_vector_type(4))) float f32x4;
typedef __attribute__((ext_vector_type(4))) unsigned int u32x4;

__device__ __forceinline__ unsigned short f2bf(float f) {
  unsigned int u = __float_as_uint(f);
  u += 0x7FFF + ((u >> 16) & 1);
  return (unsigned short)(u >> 16);
}
__device__ __forceinline__ float bflo(unsigned int v) { return __uint_as_float(v << 16); }
__device__ __forceinline__ float bfhi(unsigned int v) { return __uint_as_float(v & 0xFFFF0000u); }

// ---------------- CSR build: two-level counting sort ----------------
__global__ __launch_bounds__(256) void k_bcnt(const int* __restrict__ dst, int* __restrict__ gcnt) {
  __shared__ int c[NB];
  int tid = threadIdx.x, e0 = blockIdx.x * 4096;
  for (int i = tid; i < NB; i += 256) c[i] = 0;
  __syncthreads();
#pragma unroll
  for (int i = 0; i < 16; ++i) {
    int e = e0 + i * 256 + tid;
    if (e < N_EDGES) atomicAdd(&c[dst[e] >> 8], 1);
  }
  __syncthreads();
  for (int i = tid; i < NB; i += 256)
    if (c[i]) atomicAdd(&gcnt[i], c[i]);
}

__global__ __launch_bounds__(512) void k_bscan(const int* __restrict__ gcnt, int* __restrict__ boff,
                                               int* __restrict__ cursor) {
  __shared__ int sh[512];
  int t = threadIdx.x;
  int v = (t < NB) ? gcnt[t] : 0;
  sh[t] = v;
  __syncthreads();
  for (int s = 1; s < 512; s <<= 1) {
    int x = (t >= s) ? sh[t - s] : 0;
    __syncthreads();
    sh[t] += x;
    __syncthreads();
  }
  if (t < NB) {
    int e = sh[t] - v;
    boff[t] = e;
    cursor[t] = e;
  }
  if (t == 0) boff[NB] = N_EDGES;
}

__global__ __launch_bounds__(256) void k_bucket(const int* __restrict__ src, const int* __restrict__ dst,
                                                int* __restrict__ cursor, unsigned int* __restrict__ ebuf) {
  __shared__ int cnt[NB];
  __shared__ int base[NB];
  int tid = threadIdx.x;
  int e0 = blockIdx.x * 4096;
  for (int i = tid; i < NB; i += 256) cnt[i] = 0;
  __syncthreads();
  unsigned int pk[16];
  int bk[16], rk[16];
#pragma unroll
  for (int i = 0; i < 16; ++i) {
    int e = e0 + i * 256 + tid;
    if (e < N_EDGES) {
      int s = src[e], d = dst[e];
      bk[i] = d >> 8;
      pk[i] = ((unsigned int)(d & 255) << 17) | (unsigned int)s;
      rk[i] = atomicAdd(&cnt[bk[i]], 1);
    } else
      bk[i] = -1;
  }
  __syncthreads();
  for (int i = tid; i < NB; i += 256)
    base[i] = cnt[i] ? atomicAdd(&cursor[i], cnt[i]) : 0;
  __syncthreads();
#pragma unroll
  for (int i = 0; i < 16; ++i)
    if (bk[i] >= 0) ebuf[base[bk[i]] + rk[i]] = pk[i];
}

__global__ __launch_bounds__(256) void k_bsort(const unsigned int* __restrict__ ebuf,
                                               const int* __restrict__ boff,
                                               int* __restrict__ csr, int* __restrict__ offs) {
  __shared__ unsigned int arr[BCAP];
  __shared__ unsigned int srt[BCAP];
  __shared__ unsigned short rnk[BCAP];
  __shared__ int cnt[256];
  __shared__ int off[257];
  int b = blockIdx.x, tid = threadIdx.x;
  int beg = boff[b], end = boff[b + 1];
  int ce = min(end - beg, BCAP);
  cnt[tid] = 0;
  __syncthreads();
  for (int i = tid; i < ce; i += 256) {
    unsigned int p = ebuf[beg + i];
    arr[i] = p;
    rnk[i] = (unsigned short)atomicAdd(&cnt[p >> 17], 1);
  }
  __syncthreads();
  int v = cnt[tid];
  off[tid + 1] = v;
  if (tid == 0) off[0] = 0;
  __syncthreads();
  for (int s = 1; s < 256; s <<= 1) {
    int x = (tid + 1 > s) ? off[tid + 1 - s] : 0;
    __syncthreads();
    off[tid + 1] += x;
    __syncthreads();
  }
  for (int i = tid; i < ce; i += 256) {
    unsigned int p = arr[i];
    srt[off[p >> 17] + rnk[i]] = p & 0x1FFFF;
  }
  __syncthreads();
  for (int i = tid; i < ce; i += 256) csr[beg + i] = (int)srt[i];
  int node = (b << 8) + tid;
  if (node < N_NODES) offs[node] = beg + off[tid];
  if (b == NB - 1 && tid == 0) offs[N_NODES] = N_EDGES;
}

// ---------------- One-time weight prep: fp32 W[k][n] -> bf16 Wt[n][k] pitch 136 in global ----------------
// slot 0 = W0, slots 1..4 = W1[0..3], slots 5..8 = W2[0..3]
__global__ __launch_bounds__(256) void k_wprep(const float* __restrict__ W0, const float* __restrict__ W1,
                                               const float* __restrict__ W2, unsigned short* __restrict__ wb) {
  int m = blockIdx.x >> 3, part = blockIdx.x & 7, tid = threadIdx.x;
  const float* src = (m == 0) ? W0 : ((m <= DEPTH) ? W1 + (size_t)(m - 1) * H * H : W2 + (size_t)(m - 1 - DEPTH) * H * H);
  unsigned short* dst = wb + (size_t)m * WSLOT;
  int idx = part * 256 + tid;  // 0..2047
  int ng4 = idx & 31, kp = idx >> 5;
  float4 r0 = *(const float4*)&src[(2 * kp) * H + 4 * ng4];
  float4 r1 = *(const float4*)&src[(2 * kp + 1) * H + 4 * ng4];
  unsigned int p0 = (unsigned int)f2bf(r0.x) | ((unsigned int)f2bf(r1.x) << 16);
  unsigned int p1 = (unsigned int)f2bf(r0.y) | ((unsigned int)f2bf(r1.y) << 16);
  unsigned int p2 = (unsigned int)f2bf(r0.z) | ((unsigned int)f2bf(r1.z) << 16);
  unsigned int p3 = (unsigned int)f2bf(r0.w) | ((unsigned int)f2bf(r1.w) << 16);
  *(unsigned int*)&dst[(4 * ng4 + 0) * WPITCH + 2 * kp] = p0;
  *(unsigned int*)&dst[(4 * ng4 + 1) * WPITCH + 2 * kp] = p1;
  *(unsigned int*)&dst[(4 * ng4 + 2) * WPITCH + 2 * kp] = p2;
  *(unsigned int*)&dst[(4 * ng4 + 3) * WPITCH + 2 * kp] = p3;
}

// ---------------- stage pre-converted bf16 weights: linear conflict-free copy (512 threads) ----------------
__device__ __forceinline__ void stage_wb(const unsigned short* __restrict__ Wg, unsigned short* Wt, int tid) {
  // 2176 x 16B chunks = 34816 B
#pragma unroll
  for (int i = 0; i < 4; ++i) {
    int c = tid + i * 512;
    *(uint4*)&Wt[c * 8] = *(const uint4*)&Wg[c * 8];
  }
  int c = tid + 2048;
  if (c < 2176) *(uint4*)&Wt[c * 8] = *(const uint4*)&Wg[c * 8];
}

// ---------------- Linear 0 (MFMA): h0 = relu(x @ W0 + b0), x fp32, h0 bf16 ----------------
// 512 threads, 128 nodes/block
__global__ __launch_bounds__(512, 4) void k_lin(const float* __restrict__ in, const unsigned short* __restrict__ w0t,
                                                const float* __restrict__ bg, unsigned short* __restrict__ outp) {
  __shared__ __align__(16) unsigned short Wt[WSLOT];
  __shared__ __align__(16) unsigned short zs[128 * 136];
  int tid = threadIdx.x;
  int lane = tid & 63, w = tid >> 6;
  int q = lane >> 4, l16 = lane & 15;
  int n0 = blockIdx.x * 128;

  stage_wb(w0t, Wt, tid);

  int row = n0 + w * 16 + l16;
  int rr = (row < N_NODES) ? row : 0;
  bf16x8 afrag[4];
#pragma unroll
  for (int ks = 0; ks < 4; ++ks) {
    const float* p = &in[(size_t)rr * H + ks * 32 + q * 8];
    f32x4 f0 = __builtin_nontemporal_load((const f32x4*)p);
    f32x4 f1 = __builtin_nontemporal_load((const f32x4*)(p + 4));
    bf16x8 a;
    a[0] = (short)f2bf(f0.x); a[1] = (short)f2bf(f0.y); a[2] = (short)f2bf(f0.z); a[3] = (short)f2bf(f0.w);
    a[4] = (short)f2bf(f1.x); a[5] = (short)f2bf(f1.y); a[6] = (short)f2bf(f1.z); a[7] = (short)f2bf(f1.w);
    afrag[ks] = a;
  }
  f32x4 acc[8];
#pragma unroll
  for (int ct = 0; ct < 8; ++ct) acc[ct] = (f32x4){0.f, 0.f, 0.f, 0.f};
  __syncthreads();
#pragma unroll
  for (int ct = 0; ct < 8; ++ct)
#pragma unroll
    for (int ks = 0; ks < 4; ++ks) {
      bf16x8 b = *(bf16x8*)&Wt[(ct * 16 + l16) * WPITCH + ks * 32 + q * 8];
      acc[ct] = __builtin_amdgcn_mfma_f32_16x16x32_bf16(afrag[ks], b, acc[ct], 0, 0, 0);
    }
#pragma unroll
  for (int ct = 0; ct < 8; ++ct) {
    float bb = bg[ct * 16 + l16];
#pragma unroll
    for (int r = 0; r < 4; ++r) {
      float v = fmaxf(acc[ct][r] + bb, 0.f);
      zs[(w * 16 + q * 4 + r) * 136 + ct * 16 + l16] = f2bf(v);
    }
  }
  __syncthreads();
  int node = tid >> 2, cb = (tid & 3) * 32;
  if (n0 + node < N_NODES) {
#pragma unroll
    for (int i = 0; i < 4; ++i) {
      uint4 v = *(uint4*)&zs[node * 136 + cb + i * 8];
      *(uint4*)&outp[(size_t)(n0 + node) * H + cb + i * 8] = v;
    }
  }
}

// ---------------- Fused agg + MLP (MFMA): hout = relu( relu((hin_self+agg)@W1+b1)@W2 + b2 + h0 ) ----------------
// hin and hout are DISTINCT buffers (ping-pong) -> no cross-block RAW race.
// 512 threads, 128 nodes/block. Gather: 32 groups x 16 lanes, uint4 (16B/lane, full row per instr).
// Unroll-16 + zero-pad row at N_NODES; csr software-pipelined; launch_bounds(512,4) frees VGPRs
// so the 16 gathers actually stay in flight (round-4 regalloc collapsed them at VGPR=56).
#define ACC8(v)                                                       \
  {                                                                   \
    a0 += bflo(v.x); a1 += bfhi(v.x); a2 += bflo(v.y); a3 += bfhi(v.y); \
    a4 += bflo(v.z); a5 += bfhi(v.z); a6 += bflo(v.w); a7 += bfhi(v.w); \
  }

__global__ __launch_bounds__(512, 4) void k_mlp(const unsigned short* __restrict__ hin,
                                                const int* __restrict__ offs, const int* __restrict__ csr,
                                                const unsigned short* __restrict__ w1t, const float* __restrict__ b1g,
                                                const unsigned short* __restrict__ w2t, const float* __restrict__ b2g,
                                                const unsigned short* __restrict__ h0, unsigned short* __restrict__ hout) {
  __shared__ __align__(16) unsigned short Wt[WSLOT];
  __shared__ __align__(16) unsigned short zs[128 * 136];
  int tid = threadIdx.x;
  int n0 = blockIdx.x * 128;

  stage_wb(w1t, Wt, tid);  // loads overlap the gather below

  // ---- gather phase: z = h_self + sum_{neighbors} h, straight into zs (bf16) ----
  {
    int g = tid >> 4, l = tid & 15;
    const uint4* hu4 = (const uint4*)hin;  // row = 16 uint4
    int bn = n0 + g * 4;
    int ofs[5];
#pragma unroll
    for (int k = 0; k < 5; ++k) ofs[k] = offs[min(bn + k, N_NODES)];
    // prefetch first csr chunk of each node (independent loads, off the critical path)
    int idxp[4];
#pragma unroll
    for (int it = 0; it < 4; ++it)
      idxp[it] = (ofs[it] + l < ofs[it + 1]) ? __builtin_nontemporal_load(&csr[ofs[it] + l]) : N_NODES;
#pragma unroll
    for (int it = 0; it < 4; ++it) {
      int nl = g * 4 + it;
      int nc = min(n0 + nl, N_NODES);  // pad row (zeros) for overhang nodes
      uint4 self = hu4[(size_t)nc * 16 + l];
      float a0 = bflo(self.x), a1 = bfhi(self.x), a2 = bflo(self.y), a3 = bfhi(self.y);
      float a4 = bflo(self.z), a5 = bfhi(self.z), a6 = bflo(self.w), a7 = bfhi(self.w);
      int beg = ofs[it], end = ofs[it + 1];
      int idx = idxp[it];
      for (int e = beg; e < end; e += 16) {
        // prefetch next chunk's indices while this chunk's gathers are in flight
        int en = e + 16;
        int idxn = (en + l < end) ? __builtin_nontemporal_load(&csr[en + l]) : N_NODES;
        int s[16];
#pragma unroll
        for (int j = 0; j < 16; ++j) s[j] = __shfl(idx, j, 16);
        uint4 v[16];
#pragma unroll
        for (int j = 0; j < 16; ++j) v[j] = hu4[(size_t)s[j] * 16 + l];
#pragma unroll
        for (int j = 0; j < 16; ++j) { ACC8(v[j]) }
        idx = idxn;
      }
      unsigned int o0 = (unsigned int)f2bf(a0) | ((unsigned int)f2bf(a1) << 16);
      unsigned int o1 = (unsigned int)f2bf(a2) | ((unsigned int)f2bf(a3) << 16);
      unsigned int o2 = (unsigned int)f2bf(a4) | ((unsigned int)f2bf(a5) << 16);
      unsigned int o3 = (unsigned int)f2bf(a6) | ((unsigned int)f2bf(a7) << 16);
      uint4 o;
      o.x = o0; o.y = o1; o.z = o2; o.w = o3;
      *(uint4*)&zs[nl * 136 + l * 8] = o;
    }
  }
  __syncthreads();

  // ---- GEMM 1: relu(z @ W1 + b1) ----
  int lane = tid & 63, w = tid >> 6;
  int q = lane >> 4, l16 = lane & 15;
  bf16x8 afrag[4];
#pragma unroll
  for (int ks = 0; ks < 4; ++ks)
    afrag[ks] = *(bf16x8*)&zs[(w * 16 + l16) * 136 + ks * 32 + q * 8];

  f32x4 acc[8];
#pragma unroll
  for (int ct = 0; ct < 8; ++ct) acc[ct] = (f32x4){0.f, 0.f, 0.f, 0.f};
#pragma unroll
  for (int ct = 0; ct < 8; ++ct)
#pragma unroll
    for (int ks = 0; ks < 4; ++ks) {
      bf16x8 b = *(bf16x8*)&Wt[(ct * 16 + l16) * WPITCH + ks * 32 + q * 8];
      acc[ct] = __builtin_amdgcn_mfma_f32_16x16x32_bf16(afrag[ks], b, acc[ct], 0, 0, 0);
    }
  __syncthreads();
  stage_wb(w2t, Wt, tid);
#pragma unroll
  for (int ct = 0; ct < 8; ++ct) {
    float bb = b1g[ct * 16 + l16];
#pragma unroll
    for (int r = 0; r < 4; ++r) {
      float v = fmaxf(acc[ct][r] + bb, 0.f);
      zs[(w * 16 + q * 4 + r) * 136 + ct * 16 + l16] = f2bf(v);
    }
  }
  __syncthreads();

  // ---- GEMM 2: z1 @ W2 + b2, then +h0 residual, relu, store ----
  bf16x8 a2[4];
#pragma unroll
  for (int ks = 0; ks < 4; ++ks)
    a2[ks] = *(bf16x8*)&zs[(w * 16 + l16) * 136 + ks * 32 + q * 8];
  f32x4 acc2[8];
#pragma unroll
  for (int ct = 0; ct < 8; ++ct) acc2[ct] = (f32x4){0.f, 0.f, 0.f, 0.f};
#pragma unroll
  for (int ct = 0; ct < 8; ++ct)
#pragma unroll
    for (int ks = 0; ks < 4; ++ks) {
      bf16x8 b = *(bf16x8*)&Wt[(ct * 16 + l16) * WPITCH + ks * 32 + q * 8];
      acc2[ct] = __builtin_amdgcn_mfma_f32_16x16x32_bf16(a2[ks], b, acc2[ct], 0, 0, 0);
    }
#pragma unroll
  for (int ct = 0; ct < 8; ++ct) {
    float bb = b2g[ct * 16 + l16];
#pragma unroll
    for (int r = 0; r < 4; ++r) {
      float v = acc2[ct][r] + bb;
      zs[(w * 16 + q * 4 + r) * 136 + ct * 16 + l16] = f2bf(v);
    }
  }
  __syncthreads();
  int node = tid >> 2, cb = (tid & 3) * 32;
  if (n0 + node < N_NODES) {
    size_t base = (size_t)(n0 + node) * H + cb;
#pragma unroll
    for (int i = 0; i < 4; ++i) {
      u32x4 zv = *(u32x4*)&zs[node * 136 + cb + i * 8];
      u32x4 hv = __builtin_nontemporal_load((const u32x4*)&h0[base + i * 8]);
      u32x4 o;
#pragma unroll
      for (int j = 0; j < 4; ++j) {
        float a = fmaxf(bflo(zv[j]) + bflo(hv[j]), 0.f);
        float b = fmaxf(bfhi(zv[j]) + bfhi(hv[j]), 0.f);
        o[j] = (unsigned int)f2bf(a) | ((unsigned int)f2bf(b) << 16);
      }
      __builtin_nontemporal_store(o, (u32x4*)&hout[base + i * 8]);
    }
  }
}

// ---------------- Pooling ----------------
__global__ void k_starts(const int* __restrict__ batch, int* __restrict__ starts) {
  int n = blockIdx.x * 256 + threadIdx.x;
  if (n >= N_NODES) return;
  int b = batch[n];
  if (n == 0) {
    for (int g = 0; g <= b; ++g) starts[g] = 0;
  } else {
    int bp = batch[n - 1];
    for (int g = bp + 1; g <= b; ++g) starts[g] = n;
  }
  if (n == N_NODES - 1) {
    for (int g = b + 1; g <= N_GRAPHS; ++g) starts[g] = N_NODES;
  }
}

__global__ __launch_bounds__(256) void k_pool(const unsigned short* __restrict__ h, const int* __restrict__ starts,
                                              const float* __restrict__ Wf, const float* __restrict__ bf_,
                                              float* __restrict__ out) {
  __shared__ float r[4];
  int g = blockIdx.x, tid = threadIdx.x;
  int lane = tid & 63, w = tid >> 6;
  int beg = starts[g], end = starts[g + 1];
  const unsigned int* hu = (const unsigned int*)h;
  float sx = 0.f, sy = 0.f;
  for (int n = beg + w; n < end; n += 4) {
    unsigned int v = hu[(size_t)n * 64 + lane];
    sx += bflo(v);
    sy += bfhi(v);
  }
  float val = sx * Wf[2 * lane] + sy * Wf[2 * lane + 1];
#pragma unroll
  for (int off = 32; off > 0; off >>= 1) val += __shfl_down(val, off);
  if (lane == 0) r[w] = val;
  __syncthreads();
  if (tid == 0) out[g] = r[0] + r[1] + r[2] + r[3] + bf_[0];
}

extern "C" void kernel_launch(void* const* d_in, const int* in_sizes, int n_in,
                              void* d_out, int out_size, void* d_ws, size_t ws_size,
                              hipStream_t stream) {
  const float* x = (const float*)d_in[0];
  const int* ei = (const int*)d_in[1];
  const int* srcv = ei;
  const int* dstv = ei + N_EDGES;
  const int* batch = (const int*)d_in[3];
  const float* W0 = (const float*)d_in[4];
  const float* b0 = (const float*)d_in[5];
  const float* W1 = (const float*)d_in[6];
  const float* b1 = (const float*)d_in[7];
  const float* W2 = (const float*)d_in[8];
  const float* b2 = (const float*)d_in[9];
  const float* Wf = (const float*)d_in[10];
  const float* bf_ = (const float*)d_in[11];
  float* out = (float*)d_out;

  char* ws = (char*)d_ws;
  size_t o = 0;
  auto alloc = [&](size_t bytes) {
    size_t r = o;
    o = (o + bytes + 255) & ~(size_t)255;
    return r;
  };
  int* offs = (int*)(ws + alloc((N_NODES + 1) * sizeof(int)));
  int* gcnt = (int*)(ws + alloc(NB * sizeof(int)));
  int* boff = (int*)(ws + alloc((NB + 1) * sizeof(int)));
  int* cursor = (int*)(ws + alloc(NB * sizeof(int)));
  unsigned int* ebuf = (unsigned int*)(ws + alloc((size_t)N_EDGES * 4));
  int* csr = (int*)(ws + alloc((size_t)N_EDGES * sizeof(int)));
  int* starts = (int*)(ws + alloc((N_GRAPHS + 1) * sizeof(int)));
  // +1 zero-pad row at index N_NODES (gather target for out-of-range edge slots)
  unsigned short* h0 = (unsigned short*)(ws + alloc((size_t)(N_NODES + 1) * H * 2));
  unsigned short* hA = (unsigned short*)(ws + alloc((size_t)(N_NODES + 1) * H * 2));
  unsigned short* hB = (unsigned short*)(ws + alloc((size_t)(N_NODES + 1) * H * 2));
  unsigned short* wbuf = (unsigned short*)(ws + alloc((size_t)9 * WSLOT * 2));

  (void)hipMemsetAsync(gcnt, 0, NB * sizeof(int), stream);
  (void)hipMemsetAsync(h0 + (size_t)N_NODES * H, 0, H * 2, stream);
  (void)hipMemsetAsync(hA + (size_t)N_NODES * H, 0, H * 2, stream);
  (void)hipMemsetAsync(hB + (size_t)N_NODES * H, 0, H * 2, stream);
  k_wprep<<<72, 256, 0, stream>>>(W0, W1, W2, wbuf);
  k_bcnt<<<NB, 256, 0, stream>>>(dstv, gcnt);
  k_bscan<<<1, 512, 0, stream>>>(gcnt, boff, cursor);
  k_bucket<<<NB, 256, 0, stream>>>(srcv, dstv, cursor, ebuf);
  k_bsort<<<NB, 256, 0, stream>>>(ebuf, boff, csr, offs);
  k_starts<<<(N_NODES + 255) / 256, 256, 0, stream>>>(batch, starts);

  const int nblk = (N_NODES + 127) / 128;
  k_lin<<<nblk, 512, 0, stream>>>(x, wbuf, b0, h0);
  for (int i = 0; i < DEPTH; ++i) {
    const unsigned short* hin = (i == 0) ? h0 : ((i & 1) ? hA : hB);
    unsigned short* hout = (i & 1) ? hB : hA;
    k_mlp<<<nblk, 512, 0, stream>>>(hin, offs, csr,
                                    wbuf + (size_t)(1 + i) * WSLOT, b1 + (size_t)i * H,
                                    wbuf + (size_t)(1 + DEPTH + i) * WSLOT, b2 + (size_t)i * H,
                                    h0, hout);
  }
  k_pool<<<N_GRAPHS, 256, 0, stream>>>(hB, starts, Wf, bf_, out);
}

// Round 7
// 587.811 us; speedup vs baseline: 1.1277x; 1.1277x over previous
//
#include <hip/hip_runtime.h>

#define N_NODES 100000
#define N_EDGES 1600000
#define N_GRAPHS 1000
#define H 128
#define DEPTH 4
#define NB 391        // buckets of 256 nodes
#define BCAP 4864     // bucket capacity (mean 4096, sd 64 -> +12 sigma)
#define WPITCH 136    // bf16 pitch per output col (reads time-share bank quads = free)
#define WSLOT (H * WPITCH)  // 17408 shorts = 34816 B per weight matrix

typedef __attribute__((ext_vector_type(8))) short bf16x8;
typedef __attribute__((ext_vector_type(4))) float f32x4;
typedef __attribute__((ext_vector_type(4))) unsigned int u32x4;

__device__ __forceinline__ unsigned short f2bf(float f) {
  unsigned int u = __float_as_uint(f);
  u += 0x7FFF + ((u >> 16) & 1);
  return (unsigned short)(u >> 16);
}
__device__ __forceinline__ float bflo(unsigned int v) { return __uint_as_float(v << 16); }
__device__ __forceinline__ float bfhi(unsigned int v) { return __uint_as_float(v & 0xFFFF0000u); }

// ---------------- CSR build: two-level counting sort ----------------
__global__ __launch_bounds__(256) void k_bcnt(const int* __restrict__ dst, int* __restrict__ gcnt) {
  __shared__ int c[NB];
  int tid = threadIdx.x, e0 = blockIdx.x * 4096;
  for (int i = tid; i < NB; i += 256) c[i] = 0;
  __syncthreads();
#pragma unroll
  for (int i = 0; i < 16; ++i) {
    int e = e0 + i * 256 + tid;
    if (e < N_EDGES) atomicAdd(&c[dst[e] >> 8], 1);
  }
  __syncthreads();
  for (int i = tid; i < NB; i += 256)
    if (c[i]) atomicAdd(&gcnt[i], c[i]);
}

__global__ __launch_bounds__(512) void k_bscan(const int* __restrict__ gcnt, int* __restrict__ boff,
                                               int* __restrict__ cursor) {
  __shared__ int sh[512];
  int t = threadIdx.x;
  int v = (t < NB) ? gcnt[t] : 0;
  sh[t] = v;
  __syncthreads();
  for (int s = 1; s < 512; s <<= 1) {
    int x = (t >= s) ? sh[t - s] : 0;
    __syncthreads();
    sh[t] += x;
    __syncthreads();
  }
  if (t < NB) {
    int e = sh[t] - v;
    boff[t] = e;
    cursor[t] = e;
  }
  if (t == 0) boff[NB] = N_EDGES;
}

__global__ __launch_bounds__(256) void k_bucket(const int* __restrict__ src, const int* __restrict__ dst,
                                                int* __restrict__ cursor, unsigned int* __restrict__ ebuf) {
  __shared__ int cnt[NB];
  __shared__ int base[NB];
  int tid = threadIdx.x;
  int e0 = blockIdx.x * 4096;
  for (int i = tid; i < NB; i += 256) cnt[i] = 0;
  __syncthreads();
  unsigned int pk[16];
  int bk[16], rk[16];
#pragma unroll
  for (int i = 0; i < 16; ++i) {
    int e = e0 + i * 256 + tid;
    if (e < N_EDGES) {
      int s = src[e], d = dst[e];
      bk[i] = d >> 8;
      pk[i] = ((unsigned int)(d & 255) << 17) | (unsigned int)s;
      rk[i] = atomicAdd(&cnt[bk[i]], 1);
    } else
      bk[i] = -1;
  }
  __syncthreads();
  for (int i = tid; i < NB; i += 256)
    base[i] = cnt[i] ? atomicAdd(&cursor[i], cnt[i]) : 0;
  __syncthreads();
#pragma unroll
  for (int i = 0; i < 16; ++i)
    if (bk[i] >= 0) ebuf[base[bk[i]] + rk[i]] = pk[i];
}

__global__ __launch_bounds__(256) void k_bsort(const unsigned int* __restrict__ ebuf,
                                               const int* __restrict__ boff,
                                               int* __restrict__ csr, int* __restrict__ offs) {
  __shared__ unsigned int arr[BCAP];
  __shared__ unsigned int srt[BCAP];
  __shared__ unsigned short rnk[BCAP];
  __shared__ int cnt[256];
  __shared__ int off[257];
  int b = blockIdx.x, tid = threadIdx.x;
  int beg = boff[b], end = boff[b + 1];
  int ce = min(end - beg, BCAP);
  cnt[tid] = 0;
  __syncthreads();
  for (int i = tid; i < ce; i += 256) {
    unsigned int p = ebuf[beg + i];
    arr[i] = p;
    rnk[i] = (unsigned short)atomicAdd(&cnt[p >> 17], 1);
  }
  __syncthreads();
  int v = cnt[tid];
  off[tid + 1] = v;
  if (tid == 0) off[0] = 0;
  __syncthreads();
  for (int s = 1; s < 256; s <<= 1) {
    int x = (tid + 1 > s) ? off[tid + 1 - s] : 0;
    __syncthreads();
    off[tid + 1] += x;
    __syncthreads();
  }
  for (int i = tid; i < ce; i += 256) {
    unsigned int p = arr[i];
    srt[off[p >> 17] + rnk[i]] = p & 0x1FFFF;
  }
  __syncthreads();
  for (int i = tid; i < ce; i += 256) csr[beg + i] = (int)srt[i];
  int node = (b << 8) + tid;
  if (node < N_NODES) offs[node] = beg + off[tid];
  if (b == NB - 1 && tid == 0) offs[N_NODES] = N_EDGES;
}

// ---------------- One-time weight prep: fp32 W[k][n] -> bf16 Wt[n][k] pitch 136 in global ----------------
// slot 0 = W0, slots 1..4 = W1[0..3], slots 5..8 = W2[0..3]
__global__ __launch_bounds__(256) void k_wprep(const float* __restrict__ W0, const float* __restrict__ W1,
                                               const float* __restrict__ W2, unsigned short* __restrict__ wb) {
  int m = blockIdx.x >> 3, part = blockIdx.x & 7, tid = threadIdx.x;
  const float* src = (m == 0) ? W0 : ((m <= DEPTH) ? W1 + (size_t)(m - 1) * H * H : W2 + (size_t)(m - 1 - DEPTH) * H * H);
  unsigned short* dst = wb + (size_t)m * WSLOT;
  int idx = part * 256 + tid;  // 0..2047
  int ng4 = idx & 31, kp = idx >> 5;
  float4 r0 = *(const float4*)&src[(2 * kp) * H + 4 * ng4];
  float4 r1 = *(const float4*)&src[(2 * kp + 1) * H + 4 * ng4];
  unsigned int p0 = (unsigned int)f2bf(r0.x) | ((unsigned int)f2bf(r1.x) << 16);
  unsigned int p1 = (unsigned int)f2bf(r0.y) | ((unsigned int)f2bf(r1.y) << 16);
  unsigned int p2 = (unsigned int)f2bf(r0.z) | ((unsigned int)f2bf(r1.z) << 16);
  unsigned int p3 = (unsigned int)f2bf(r0.w) | ((unsigned int)f2bf(r1.w) << 16);
  *(unsigned int*)&dst[(4 * ng4 + 0) * WPITCH + 2 * kp] = p0;
  *(unsigned int*)&dst[(4 * ng4 + 1) * WPITCH + 2 * kp] = p1;
  *(unsigned int*)&dst[(4 * ng4 + 2) * WPITCH + 2 * kp] = p2;
  *(unsigned int*)&dst[(4 * ng4 + 3) * WPITCH + 2 * kp] = p3;
}

// ---------------- stage pre-converted bf16 weights: linear conflict-free copy (512 threads) ----------------
__device__ __forceinline__ void stage_wb(const unsigned short* __restrict__ Wg, unsigned short* Wt, int tid) {
  // 2176 x 16B chunks = 34816 B
#pragma unroll
  for (int i = 0; i < 4; ++i) {
    int c = tid + i * 512;
    *(uint4*)&Wt[c * 8] = *(const uint4*)&Wg[c * 8];
  }
  int c = tid + 2048;
  if (c < 2176) *(uint4*)&Wt[c * 8] = *(const uint4*)&Wg[c * 8];
}

// ---------------- Linear 0 (MFMA): h0 = relu(x @ W0 + b0), x fp32, h0 bf16 ----------------
// 512 threads, 128 nodes/block
__global__ __launch_bounds__(512, 4) void k_lin(const float* __restrict__ in, const unsigned short* __restrict__ w0t,
                                                const float* __restrict__ bg, unsigned short* __restrict__ outp) {
  __shared__ __align__(16) unsigned short Wt[WSLOT];
  __shared__ __align__(16) unsigned short zs[128 * 136];
  int tid = threadIdx.x;
  int lane = tid & 63, w = tid >> 6;
  int q = lane >> 4, l16 = lane & 15;
  int n0 = blockIdx.x * 128;

  stage_wb(w0t, Wt, tid);

  int row = n0 + w * 16 + l16;
  int rr = (row < N_NODES) ? row : 0;
  bf16x8 afrag[4];
#pragma unroll
  for (int ks = 0; ks < 4; ++ks) {
    const float* p = &in[(size_t)rr * H + ks * 32 + q * 8];
    f32x4 f0 = __builtin_nontemporal_load((const f32x4*)p);
    f32x4 f1 = __builtin_nontemporal_load((const f32x4*)(p + 4));
    bf16x8 a;
    a[0] = (short)f2bf(f0.x); a[1] = (short)f2bf(f0.y); a[2] = (short)f2bf(f0.z); a[3] = (short)f2bf(f0.w);
    a[4] = (short)f2bf(f1.x); a[5] = (short)f2bf(f1.y); a[6] = (short)f2bf(f1.z); a[7] = (short)f2bf(f1.w);
    afrag[ks] = a;
  }
  f32x4 acc[8];
#pragma unroll
  for (int ct = 0; ct < 8; ++ct) acc[ct] = (f32x4){0.f, 0.f, 0.f, 0.f};
  __syncthreads();
#pragma unroll
  for (int ct = 0; ct < 8; ++ct)
#pragma unroll
    for (int ks = 0; ks < 4; ++ks) {
      bf16x8 b = *(bf16x8*)&Wt[(ct * 16 + l16) * WPITCH + ks * 32 + q * 8];
      acc[ct] = __builtin_amdgcn_mfma_f32_16x16x32_bf16(afrag[ks], b, acc[ct], 0, 0, 0);
    }
#pragma unroll
  for (int ct = 0; ct < 8; ++ct) {
    float bb = bg[ct * 16 + l16];
#pragma unroll
    for (int r = 0; r < 4; ++r) {
      float v = fmaxf(acc[ct][r] + bb, 0.f);
      zs[(w * 16 + q * 4 + r) * 136 + ct * 16 + l16] = f2bf(v);
    }
  }
  __syncthreads();
  int node = tid >> 2, cb = (tid & 3) * 32;
  if (n0 + node < N_NODES) {
#pragma unroll
    for (int i = 0; i < 4; ++i) {
      uint4 v = *(uint4*)&zs[node * 136 + cb + i * 8];
      *(uint4*)&outp[(size_t)(n0 + node) * H + cb + i * 8] = v;
    }
  }
}

// ---------------- Fused agg + MLP (MFMA): hout = relu( relu((hin_self+agg)@W1+b1)@W2 + b2 + h0 ) ----------------
// hin and hout are DISTINCT buffers (ping-pong) -> no cross-block RAW race.
// 512 threads, 128 nodes/block. Gather: 32 groups x 16 lanes, uint4 (16B/lane, full row per instr).
// Unroll-16 + zero-pad row at N_NODES; csr software-pipelined.
// NOTE (round-6 post-mortem): nontemporal store on hout tripled WRITE_SIZE (25->68MB, +18us)
// and NT loads on csr/h0 cost ~5MB FETCH -- all reverted to plain cached accesses.
#define ACC8(v)                                                       \
  {                                                                   \
    a0 += bflo(v.x); a1 += bfhi(v.x); a2 += bflo(v.y); a3 += bfhi(v.y); \
    a4 += bflo(v.z); a5 += bfhi(v.z); a6 += bflo(v.w); a7 += bfhi(v.w); \
  }

__global__ __launch_bounds__(512, 4) void k_mlp(const unsigned short* __restrict__ hin,
                                                const int* __restrict__ offs, const int* __restrict__ csr,
                                                const unsigned short* __restrict__ w1t, const float* __restrict__ b1g,
                                                const unsigned short* __restrict__ w2t, const float* __restrict__ b2g,
                                                const unsigned short* __restrict__ h0, unsigned short* __restrict__ hout) {
  __shared__ __align__(16) unsigned short Wt[WSLOT];
  __shared__ __align__(16) unsigned short zs[128 * 136];
  int tid = threadIdx.x;
  int n0 = blockIdx.x * 128;

  stage_wb(w1t, Wt, tid);  // loads overlap the gather below

  // ---- gather phase: z = h_self + sum_{neighbors} h, straight into zs (bf16) ----
  {
    int g = tid >> 4, l = tid & 15;
    const uint4* hu4 = (const uint4*)hin;  // row = 16 uint4
    int bn = n0 + g * 4;
    int ofs[5];
#pragma unroll
    for (int k = 0; k < 5; ++k) ofs[k] = offs[min(bn + k, N_NODES)];
    // prefetch first csr chunk of each node (independent loads, off the critical path)
    int idxp[4];
#pragma unroll
    for (int it = 0; it < 4; ++it)
      idxp[it] = (ofs[it] + l < ofs[it + 1]) ? csr[ofs[it] + l] : N_NODES;
#pragma unroll
    for (int it = 0; it < 4; ++it) {
      int nl = g * 4 + it;
      int nc = min(n0 + nl, N_NODES);  // pad row (zeros) for overhang nodes
      uint4 self = hu4[(size_t)nc * 16 + l];
      float a0 = bflo(self.x), a1 = bfhi(self.x), a2 = bflo(self.y), a3 = bfhi(self.y);
      float a4 = bflo(self.z), a5 = bfhi(self.z), a6 = bflo(self.w), a7 = bfhi(self.w);
      int beg = ofs[it], end = ofs[it + 1];
      int idx = idxp[it];
      for (int e = beg; e < end; e += 16) {
        // prefetch next chunk's indices while this chunk's gathers are in flight
        int en = e + 16;
        int idxn = (en + l < end) ? csr[en + l] : N_NODES;
        int s[16];
#pragma unroll
        for (int j = 0; j < 16; ++j) s[j] = __shfl(idx, j, 16);
        uint4 v[16];
#pragma unroll
        for (int j = 0; j < 16; ++j) v[j] = hu4[(size_t)s[j] * 16 + l];
#pragma unroll
        for (int j = 0; j < 16; ++j) { ACC8(v[j]) }
        idx = idxn;
      }
      unsigned int o0 = (unsigned int)f2bf(a0) | ((unsigned int)f2bf(a1) << 16);
      unsigned int o1 = (unsigned int)f2bf(a2) | ((unsigned int)f2bf(a3) << 16);
      unsigned int o2 = (unsigned int)f2bf(a4) | ((unsigned int)f2bf(a5) << 16);
      unsigned int o3 = (unsigned int)f2bf(a6) | ((unsigned int)f2bf(a7) << 16);
      uint4 o;
      o.x = o0; o.y = o1; o.z = o2; o.w = o3;
      *(uint4*)&zs[nl * 136 + l * 8] = o;
    }
  }
  __syncthreads();

  // ---- GEMM 1: relu(z @ W1 + b1) ----
  int lane = tid & 63, w = tid >> 6;
  int q = lane >> 4, l16 = lane & 15;
  bf16x8 afrag[4];
#pragma unroll
  for (int ks = 0; ks < 4; ++ks)
    afrag[ks] = *(bf16x8*)&zs[(w * 16 + l16) * 136 + ks * 32 + q * 8];

  f32x4 acc[8];
#pragma unroll
  for (int ct = 0; ct < 8; ++ct) acc[ct] = (f32x4){0.f, 0.f, 0.f, 0.f};
#pragma unroll
  for (int ct = 0; ct < 8; ++ct)
#pragma unroll
    for (int ks = 0; ks < 4; ++ks) {
      bf16x8 b = *(bf16x8*)&Wt[(ct * 16 + l16) * WPITCH + ks * 32 + q * 8];
      acc[ct] = __builtin_amdgcn_mfma_f32_16x16x32_bf16(afrag[ks], b, acc[ct], 0, 0, 0);
    }
  __syncthreads();
  stage_wb(w2t, Wt, tid);
#pragma unroll
  for (int ct = 0; ct < 8; ++ct) {
    float bb = b1g[ct * 16 + l16];
#pragma unroll
    for (int r = 0; r < 4; ++r) {
      float v = fmaxf(acc[ct][r] + bb, 0.f);
      zs[(w * 16 + q * 4 + r) * 136 + ct * 16 + l16] = f2bf(v);
    }
  }
  __syncthreads();

  // ---- GEMM 2: z1 @ W2 + b2, then +h0 residual, relu, store ----
  bf16x8 a2[4];
#pragma unroll
  for (int ks = 0; ks < 4; ++ks)
    a2[ks] = *(bf16x8*)&zs[(w * 16 + l16) * 136 + ks * 32 + q * 8];
  f32x4 acc2[8];
#pragma unroll
  for (int ct = 0; ct < 8; ++ct) acc2[ct] = (f32x4){0.f, 0.f, 0.f, 0.f};
#pragma unroll
  for (int ct = 0; ct < 8; ++ct)
#pragma unroll
    for (int ks = 0; ks < 4; ++ks) {
      bf16x8 b = *(bf16x8*)&Wt[(ct * 16 + l16) * WPITCH + ks * 32 + q * 8];
      acc2[ct] = __builtin_amdgcn_mfma_f32_16x16x32_bf16(a2[ks], b, acc2[ct], 0, 0, 0);
    }
#pragma unroll
  for (int ct = 0; ct < 8; ++ct) {
    float bb = b2g[ct * 16 + l16];
#pragma unroll
    for (int r = 0; r < 4; ++r) {
      float v = acc2[ct][r] + bb;
      zs[(w * 16 + q * 4 + r) * 136 + ct * 16 + l16] = f2bf(v);
    }
  }
  __syncthreads();
  int node = tid >> 2, cb = (tid & 3) * 32;
  if (n0 + node < N_NODES) {
    size_t base = (size_t)(n0 + node) * H + cb;
#pragma unroll
    for (int i = 0; i < 4; ++i) {
      u32x4 zv = *(u32x4*)&zs[node * 136 + cb + i * 8];
      u32x4 hv = *(const u32x4*)&h0[base + i * 8];
      u32x4 o;
#pragma unroll
      for (int j = 0; j < 4; ++j) {
        float a = fmaxf(bflo(zv[j]) + bflo(hv[j]), 0.f);
        float b = fmaxf(bfhi(zv[j]) + bfhi(hv[j]), 0.f);
        o[j] = (unsigned int)f2bf(a) | ((unsigned int)f2bf(b) << 16);
      }
      *(u32x4*)&hout[base + i * 8] = o;
    }
  }
}

// ---------------- Pooling ----------------
__global__ void k_starts(const int* __restrict__ batch, int* __restrict__ starts) {
  int n = blockIdx.x * 256 + threadIdx.x;
  if (n >= N_NODES) return;
  int b = batch[n];
  if (n == 0) {
    for (int g = 0; g <= b; ++g) starts[g] = 0;
  } else {
    int bp = batch[n - 1];
    for (int g = bp + 1; g <= b; ++g) starts[g] = n;
  }
  if (n == N_NODES - 1) {
    for (int g = b + 1; g <= N_GRAPHS; ++g) starts[g] = N_NODES;
  }
}

__global__ __launch_bounds__(256) void k_pool(const unsigned short* __restrict__ h, const int* __restrict__ starts,
                                              const float* __restrict__ Wf, const float* __restrict__ bf_,
                                              float* __restrict__ out) {
  __shared__ float r[4];
  int g = blockIdx.x, tid = threadIdx.x;
  int lane = tid & 63, w = tid >> 6;
  int beg = starts[g], end = starts[g + 1];
  const unsigned int* hu = (const unsigned int*)h;
  float sx = 0.f, sy = 0.f;
  for (int n = beg + w; n < end; n += 4) {
    unsigned int v = hu[(size_t)n * 64 + lane];
    sx += bflo(v);
    sy += bfhi(v);
  }
  float val = sx * Wf[2 * lane] + sy * Wf[2 * lane + 1];
#pragma unroll
  for (int off = 32; off > 0; off >>= 1) val += __shfl_down(val, off);
  if (lane == 0) r[w] = val;
  __syncthreads();
  if (tid == 0) out[g] = r[0] + r[1] + r[2] + r[3] + bf_[0];
}

extern "C" void kernel_launch(void* const* d_in, const int* in_sizes, int n_in,
                              void* d_out, int out_size, void* d_ws, size_t ws_size,
                              hipStream_t stream) {
  const float* x = (const float*)d_in[0];
  const int* ei = (const int*)d_in[1];
  const int* srcv = ei;
  const int* dstv = ei + N_EDGES;
  const int* batch = (const int*)d_in[3];
  const float* W0 = (const float*)d_in[4];
  const float* b0 = (const float*)d_in[5];
  const float* W1 = (const float*)d_in[6];
  const float* b1 = (const float*)d_in[7];
  const float* W2 = (const float*)d_in[8];
  const float* b2 = (const float*)d_in[9];
  const float* Wf = (const float*)d_in[10];
  const float* bf_ = (const float*)d_in[11];
  float* out = (float*)d_out;

  char* ws = (char*)d_ws;
  size_t o = 0;
  auto alloc = [&](size_t bytes) {
    size_t r = o;
    o = (o + bytes + 255) & ~(size_t)255;
    return r;
  };
  int* offs = (int*)(ws + alloc((N_NODES + 1) * sizeof(int)));
  int* gcnt = (int*)(ws + alloc(NB * sizeof(int)));
  int* boff = (int*)(ws + alloc((NB + 1) * sizeof(int)));
  int* cursor = (int*)(ws + alloc(NB * sizeof(int)));
  unsigned int* ebuf = (unsigned int*)(ws + alloc((size_t)N_EDGES * 4));
  int* csr = (int*)(ws + alloc((size_t)N_EDGES * sizeof(int)));
  int* starts = (int*)(ws + alloc((N_GRAPHS + 1) * sizeof(int)));
  // +1 zero-pad row at index N_NODES (gather target for out-of-range edge slots)
  unsigned short* h0 = (unsigned short*)(ws + alloc((size_t)(N_NODES + 1) * H * 2));
  unsigned short* hA = (unsigned short*)(ws + alloc((size_t)(N_NODES + 1) * H * 2));
  unsigned short* hB = (unsigned short*)(ws + alloc((size_t)(N_NODES + 1) * H * 2));
  unsigned short* wbuf = (unsigned short*)(ws + alloc((size_t)9 * WSLOT * 2));

  (void)hipMemsetAsync(gcnt, 0, NB * sizeof(int), stream);
  (void)hipMemsetAsync(h0 + (size_t)N_NODES * H, 0, H * 2, stream);
  (void)hipMemsetAsync(hA + (size_t)N_NODES * H, 0, H * 2, stream);
  (void)hipMemsetAsync(hB + (size_t)N_NODES * H, 0, H * 2, stream);
  k_wprep<<<72, 256, 0, stream>>>(W0, W1, W2, wbuf);
  k_bcnt<<<NB, 256, 0, stream>>>(dstv, gcnt);
  k_bscan<<<1, 512, 0, stream>>>(gcnt, boff, cursor);
  k_bucket<<<NB, 256, 0, stream>>>(srcv, dstv, cursor, ebuf);
  k_bsort<<<NB, 256, 0, stream>>>(ebuf, boff, csr, offs);
  k_starts<<<(N_NODES + 255) / 256, 256, 0, stream>>>(batch, starts);

  const int nblk = (N_NODES + 127) / 128;
  k_lin<<<nblk, 512, 0, stream>>>(x, wbuf, b0, h0);
  for (int i = 0; i < DEPTH; ++i) {
    const unsigned short* hin = (i == 0) ? h0 : ((i & 1) ? hA : hB);
    unsigned short* hout = (i & 1) ? hB : hA;
    k_mlp<<<nblk, 512, 0, stream>>>(hin, offs, csr,
                                    wbuf + (size_t)(1 + i) * WSLOT, b1 + (size_t)i * H,
                                    wbuf + (size_t)(1 + DEPTH + i) * WSLOT, b2 + (size_t)i * H,
                                    h0, hout);
  }
  k_pool<<<N_GRAPHS, 256, 0, stream>>>(hB, starts, Wf, bf_, out);
}

// Round 8
// 575.928 us; speedup vs baseline: 1.1510x; 1.0206x over previous
//
#include <hip/hip_runtime.h>

#define N_NODES 100000
#define N_EDGES 1600000
#define N_GRAPHS 1000
#define H 128
#define DEPTH 4
#define NB 391        // buckets of 256 nodes
#define BCAP 4864     // bucket capacity (mean 4096, sd 64 -> +12 sigma)
#define WPITCH 136    // bf16 pitch per output col (reads time-share bank quads = free)
#define WSLOT (H * WPITCH)  // 17408 shorts = 34816 B per weight matrix

typedef __attribute__((ext_vector_type(8))) short bf16x8;
typedef __attribute__((ext_vector_type(4))) float f32x4;
typedef __attribute__((ext_vector_type(4))) unsigned int u32x4;

__device__ __forceinline__ unsigned short f2bf(float f) {
  unsigned int u = __float_as_uint(f);
  u += 0x7FFF + ((u >> 16) & 1);
  return (unsigned short)(u >> 16);
}
__device__ __forceinline__ float bflo(unsigned int v) { return __uint_as_float(v << 16); }
__device__ __forceinline__ float bfhi(unsigned int v) { return __uint_as_float(v & 0xFFFF0000u); }

// ---------------- CSR build: single-pass bucket (fixed-capacity slots) + per-bucket sort ----------------
// k_bcnt eliminated (round-8): k_bucket claims base slots in ebuf[b*BCAP+..] via one global
// atomicAdd per touched bucket; gcnt doubles as the bucket-count output.
__global__ __launch_bounds__(512) void k_bscan(const int* __restrict__ gcnt, int* __restrict__ boff) {
  __shared__ int sh[512];
  int t = threadIdx.x;
  int v = (t < NB) ? gcnt[t] : 0;
  sh[t] = v;
  __syncthreads();
  for (int s = 1; s < 512; s <<= 1) {
    int x = (t >= s) ? sh[t - s] : 0;
    __syncthreads();
    sh[t] += x;
    __syncthreads();
  }
  if (t < NB) boff[t] = sh[t] - v;
  if (t == 0) boff[NB] = N_EDGES;
}

__global__ __launch_bounds__(256) void k_bucket(const int* __restrict__ src, const int* __restrict__ dst,
                                                int* __restrict__ gcnt, unsigned int* __restrict__ ebuf) {
  __shared__ int cnt[NB];
  __shared__ int base[NB];
  int tid = threadIdx.x;
  int e0 = blockIdx.x * 4096;
  for (int i = tid; i < NB; i += 256) cnt[i] = 0;
  __syncthreads();
  unsigned int pk[16];
  int bk[16], rk[16];
#pragma unroll
  for (int i = 0; i < 16; ++i) {
    int e = e0 + i * 256 + tid;
    if (e < N_EDGES) {
      int s = src[e], d = dst[e];
      bk[i] = d >> 8;
      pk[i] = ((unsigned int)(d & 255) << 17) | (unsigned int)s;
      rk[i] = atomicAdd(&cnt[bk[i]], 1);
    } else
      bk[i] = -1;
  }
  __syncthreads();
  for (int i = tid; i < NB; i += 256)
    base[i] = cnt[i] ? atomicAdd(&gcnt[i], cnt[i]) : 0;
  __syncthreads();
#pragma unroll
  for (int i = 0; i < 16; ++i)
    if (bk[i] >= 0) ebuf[(size_t)bk[i] * BCAP + base[bk[i]] + rk[i]] = pk[i];
}

__global__ __launch_bounds__(256) void k_bsort(const unsigned int* __restrict__ ebuf,
                                               const int* __restrict__ gcnt, const int* __restrict__ boff,
                                               int* __restrict__ csr, int* __restrict__ offs) {
  __shared__ unsigned int arr[BCAP];
  __shared__ unsigned int srt[BCAP];
  __shared__ unsigned short rnk[BCAP];
  __shared__ int cnt[256];
  __shared__ int off[257];
  int b = blockIdx.x, tid = threadIdx.x;
  int beg = boff[b];
  int ce = min(gcnt[b], BCAP);
  cnt[tid] = 0;
  __syncthreads();
  for (int i = tid; i < ce; i += 256) {
    unsigned int p = ebuf[(size_t)b * BCAP + i];
    arr[i] = p;
    rnk[i] = (unsigned short)atomicAdd(&cnt[p >> 17], 1);
  }
  __syncthreads();
  int v = cnt[tid];
  off[tid + 1] = v;
  if (tid == 0) off[0] = 0;
  __syncthreads();
  for (int s = 1; s < 256; s <<= 1) {
    int x = (tid + 1 > s) ? off[tid + 1 - s] : 0;
    __syncthreads();
    off[tid + 1] += x;
    __syncthreads();
  }
  for (int i = tid; i < ce; i += 256) {
    unsigned int p = arr[i];
    srt[off[p >> 17] + rnk[i]] = p & 0x1FFFF;
  }
  __syncthreads();
  for (int i = tid; i < ce; i += 256) csr[beg + i] = (int)srt[i];
  int node = (b << 8) + tid;
  if (node < N_NODES) offs[node] = beg + off[tid];
  if (b == NB - 1 && tid == 0) offs[N_NODES] = N_EDGES;
}

// ---------------- One-time weight prep: fp32 W[k][n] -> bf16 Wt[n][k] pitch 136 in global ----------------
// slot 0 = W0, slots 1..4 = W1[0..3], slots 5..8 = W2[0..3]
__global__ __launch_bounds__(256) void k_wprep(const float* __restrict__ W0, const float* __restrict__ W1,
                                               const float* __restrict__ W2, unsigned short* __restrict__ wb) {
  int m = blockIdx.x >> 3, part = blockIdx.x & 7, tid = threadIdx.x;
  const float* src = (m == 0) ? W0 : ((m <= DEPTH) ? W1 + (size_t)(m - 1) * H * H : W2 + (size_t)(m - 1 - DEPTH) * H * H);
  unsigned short* dst = wb + (size_t)m * WSLOT;
  int idx = part * 256 + tid;  // 0..2047
  int ng4 = idx & 31, kp = idx >> 5;
  float4 r0 = *(const float4*)&src[(2 * kp) * H + 4 * ng4];
  float4 r1 = *(const float4*)&src[(2 * kp + 1) * H + 4 * ng4];
  unsigned int p0 = (unsigned int)f2bf(r0.x) | ((unsigned int)f2bf(r1.x) << 16);
  unsigned int p1 = (unsigned int)f2bf(r0.y) | ((unsigned int)f2bf(r1.y) << 16);
  unsigned int p2 = (unsigned int)f2bf(r0.z) | ((unsigned int)f2bf(r1.z) << 16);
  unsigned int p3 = (unsigned int)f2bf(r0.w) | ((unsigned int)f2bf(r1.w) << 16);
  *(unsigned int*)&dst[(4 * ng4 + 0) * WPITCH + 2 * kp] = p0;
  *(unsigned int*)&dst[(4 * ng4 + 1) * WPITCH + 2 * kp] = p1;
  *(unsigned int*)&dst[(4 * ng4 + 2) * WPITCH + 2 * kp] = p2;
  *(unsigned int*)&dst[(4 * ng4 + 3) * WPITCH + 2 * kp] = p3;
}

// ---------------- stage pre-converted bf16 weights: linear conflict-free copy (512 threads) ----------------
__device__ __forceinline__ void stage_wb(const unsigned short* __restrict__ Wg, unsigned short* Wt, int tid) {
  // 2176 x 16B chunks = 34816 B
#pragma unroll
  for (int i = 0; i < 4; ++i) {
    int c = tid + i * 512;
    *(uint4*)&Wt[c * 8] = *(const uint4*)&Wg[c * 8];
  }
  int c = tid + 2048;
  if (c < 2176) *(uint4*)&Wt[c * 8] = *(const uint4*)&Wg[c * 8];
}

// ---------------- Linear 0 (MFMA): h0 = relu(x @ W0 + b0), x fp32, h0 bf16 ----------------
// 512 threads, 128 nodes/block
__global__ __launch_bounds__(512, 4) void k_lin(const float* __restrict__ in, const unsigned short* __restrict__ w0t,
                                                const float* __restrict__ bg, unsigned short* __restrict__ outp) {
  __shared__ __align__(16) unsigned short Wt[WSLOT];
  __shared__ __align__(16) unsigned short zs[128 * 136];
  int tid = threadIdx.x;
  int lane = tid & 63, w = tid >> 6;
  int q = lane >> 4, l16 = lane & 15;
  int n0 = blockIdx.x * 128;

  stage_wb(w0t, Wt, tid);

  int row = n0 + w * 16 + l16;
  int rr = (row < N_NODES) ? row : 0;
  bf16x8 afrag[4];
#pragma unroll
  for (int ks = 0; ks < 4; ++ks) {
    const float* p = &in[(size_t)rr * H + ks * 32 + q * 8];
    f32x4 f0 = __builtin_nontemporal_load((const f32x4*)p);
    f32x4 f1 = __builtin_nontemporal_load((const f32x4*)(p + 4));
    bf16x8 a;
    a[0] = (short)f2bf(f0.x); a[1] = (short)f2bf(f0.y); a[2] = (short)f2bf(f0.z); a[3] = (short)f2bf(f0.w);
    a[4] = (short)f2bf(f1.x); a[5] = (short)f2bf(f1.y); a[6] = (short)f2bf(f1.z); a[7] = (short)f2bf(f1.w);
    afrag[ks] = a;
  }
  f32x4 acc[8];
#pragma unroll
  for (int ct = 0; ct < 8; ++ct) acc[ct] = (f32x4){0.f, 0.f, 0.f, 0.f};
  __syncthreads();
#pragma unroll
  for (int ct = 0; ct < 8; ++ct)
#pragma unroll
    for (int ks = 0; ks < 4; ++ks) {
      bf16x8 b = *(bf16x8*)&Wt[(ct * 16 + l16) * WPITCH + ks * 32 + q * 8];
      acc[ct] = __builtin_amdgcn_mfma_f32_16x16x32_bf16(afrag[ks], b, acc[ct], 0, 0, 0);
    }
#pragma unroll
  for (int ct = 0; ct < 8; ++ct) {
    float bb = bg[ct * 16 + l16];
#pragma unroll
    for (int r = 0; r < 4; ++r) {
      float v = fmaxf(acc[ct][r] + bb, 0.f);
      zs[(w * 16 + q * 4 + r) * 136 + ct * 16 + l16] = f2bf(v);
    }
  }
  __syncthreads();
  int node = tid >> 2, cb = (tid & 3) * 32;
  if (n0 + node < N_NODES) {
#pragma unroll
    for (int i = 0; i < 4; ++i) {
      uint4 v = *(uint4*)&zs[node * 136 + cb + i * 8];
      *(uint4*)&outp[(size_t)(n0 + node) * H + cb + i * 8] = v;
    }
  }
}

// ---------------- Fused agg + MLP (MFMA): hout = relu( relu((hin_self+agg)@W1+b1)@W2 + b2 + h0 ) ----------------
// hin and hout are DISTINCT buffers (ping-pong) -> no cross-block RAW race.
// 512 threads, 128 nodes/block. Gather: 32 groups x 16 lanes, uint4 (16B/lane, full row per instr).
// Unroll-16 + zero-pad row at N_NODES; csr software-pipelined. Gather is at the random-256B
// fabric service ceiling (~2.7 TB/s, FETCH at per-XCD compulsory floor) -- rounds 3,4,6,7 invariant.
#define ACC8(v)                                                       \
  {                                                                   \
    a0 += bflo(v.x); a1 += bfhi(v.x); a2 += bflo(v.y); a3 += bfhi(v.y); \
    a4 += bflo(v.z); a5 += bfhi(v.z); a6 += bflo(v.w); a7 += bfhi(v.w); \
  }

__global__ __launch_bounds__(512, 4) void k_mlp(const unsigned short* __restrict__ hin,
                                                const int* __restrict__ offs, const int* __restrict__ csr,
                                                const unsigned short* __restrict__ w1t, const float* __restrict__ b1g,
                                                const unsigned short* __restrict__ w2t, const float* __restrict__ b2g,
                                                const unsigned short* __restrict__ h0, unsigned short* __restrict__ hout) {
  __shared__ __align__(16) unsigned short Wt[WSLOT];
  __shared__ __align__(16) unsigned short zs[128 * 136];
  int tid = threadIdx.x;
  int n0 = blockIdx.x * 128;

  stage_wb(w1t, Wt, tid);  // loads overlap the gather below

  // ---- gather phase: z = h_self + sum_{neighbors} h, straight into zs (bf16) ----
  {
    int g = tid >> 4, l = tid & 15;
    const uint4* hu4 = (const uint4*)hin;  // row = 16 uint4
    int bn = n0 + g * 4;
    int ofs[5];
#pragma unroll
    for (int k = 0; k < 5; ++k) ofs[k] = offs[min(bn + k, N_NODES)];
    // prefetch first csr chunk of each node (independent loads, off the critical path)
    int idxp[4];
#pragma unroll
    for (int it = 0; it < 4; ++it)
      idxp[it] = (ofs[it] + l < ofs[it + 1]) ? csr[ofs[it] + l] : N_NODES;
#pragma unroll
    for (int it = 0; it < 4; ++it) {
      int nl = g * 4 + it;
      int nc = min(n0 + nl, N_NODES);  // pad row (zeros) for overhang nodes
      uint4 self = hu4[(size_t)nc * 16 + l];
      float a0 = bflo(self.x), a1 = bfhi(self.x), a2 = bflo(self.y), a3 = bfhi(self.y);
      float a4 = bflo(self.z), a5 = bfhi(self.z), a6 = bflo(self.w), a7 = bfhi(self.w);
      int beg = ofs[it], end = ofs[it + 1];
      int idx = idxp[it];
      for (int e = beg; e < end; e += 16) {
        // prefetch next chunk's indices while this chunk's gathers are in flight
        int en = e + 16;
        int idxn = (en + l < end) ? csr[en + l] : N_NODES;
        int s[16];
#pragma unroll
        for (int j = 0; j < 16; ++j) s[j] = __shfl(idx, j, 16);
        uint4 v[16];
#pragma unroll
        for (int j = 0; j < 16; ++j) v[j] = hu4[(size_t)s[j] * 16 + l];
#pragma unroll
        for (int j = 0; j < 16; ++j) { ACC8(v[j]) }
        idx = idxn;
      }
      unsigned int o0 = (unsigned int)f2bf(a0) | ((unsigned int)f2bf(a1) << 16);
      unsigned int o1 = (unsigned int)f2bf(a2) | ((unsigned int)f2bf(a3) << 16);
      unsigned int o2 = (unsigned int)f2bf(a4) | ((unsigned int)f2bf(a5) << 16);
      unsigned int o3 = (unsigned int)f2bf(a6) | ((unsigned int)f2bf(a7) << 16);
      uint4 o;
      o.x = o0; o.y = o1; o.z = o2; o.w = o3;
      *(uint4*)&zs[nl * 136 + l * 8] = o;
    }
  }
  __syncthreads();

  // ---- GEMM 1: relu(z @ W1 + b1) ----
  int lane = tid & 63, w = tid >> 6;
  int q = lane >> 4, l16 = lane & 15;
  bf16x8 afrag[4];
#pragma unroll
  for (int ks = 0; ks < 4; ++ks)
    afrag[ks] = *(bf16x8*)&zs[(w * 16 + l16) * 136 + ks * 32 + q * 8];

  f32x4 acc[8];
#pragma unroll
  for (int ct = 0; ct < 8; ++ct) acc[ct] = (f32x4){0.f, 0.f, 0.f, 0.f};
#pragma unroll
  for (int ct = 0; ct < 8; ++ct)
#pragma unroll
    for (int ks = 0; ks < 4; ++ks) {
      bf16x8 b = *(bf16x8*)&Wt[(ct * 16 + l16) * WPITCH + ks * 32 + q * 8];
      acc[ct] = __builtin_amdgcn_mfma_f32_16x16x32_bf16(afrag[ks], b, acc[ct], 0, 0, 0);
    }
  __syncthreads();
  stage_wb(w2t, Wt, tid);
#pragma unroll
  for (int ct = 0; ct < 8; ++ct) {
    float bb = b1g[ct * 16 + l16];
#pragma unroll
    for (int r = 0; r < 4; ++r) {
      float v = fmaxf(acc[ct][r] + bb, 0.f);
      zs[(w * 16 + q * 4 + r) * 136 + ct * 16 + l16] = f2bf(v);
    }
  }
  __syncthreads();

  // ---- GEMM 2: z1 @ W2 + b2, then +h0 residual, relu, store ----
  bf16x8 a2[4];
#pragma unroll
  for (int ks = 0; ks < 4; ++ks)
    a2[ks] = *(bf16x8*)&zs[(w * 16 + l16) * 136 + ks * 32 + q * 8];
  f32x4 acc2[8];
#pragma unroll
  for (int ct = 0; ct < 8; ++ct) acc2[ct] = (f32x4){0.f, 0.f, 0.f, 0.f};
#pragma unroll
  for (int ct = 0; ct < 8; ++ct)
#pragma unroll
    for (int ks = 0; ks < 4; ++ks) {
      bf16x8 b = *(bf16x8*)&Wt[(ct * 16 + l16) * WPITCH + ks * 32 + q * 8];
      acc2[ct] = __builtin_amdgcn_mfma_f32_16x16x32_bf16(a2[ks], b, acc2[ct], 0, 0, 0);
    }
#pragma unroll
  for (int ct = 0; ct < 8; ++ct) {
    float bb = b2g[ct * 16 + l16];
#pragma unroll
    for (int r = 0; r < 4; ++r) {
      float v = acc2[ct][r] + bb;
      zs[(w * 16 + q * 4 + r) * 136 + ct * 16 + l16] = f2bf(v);
    }
  }
  __syncthreads();
  int node = tid >> 2, cb = (tid & 3) * 32;
  if (n0 + node < N_NODES) {
    size_t base = (size_t)(n0 + node) * H + cb;
#pragma unroll
    for (int i = 0; i < 4; ++i) {
      u32x4 zv = *(u32x4*)&zs[node * 136 + cb + i * 8];
      u32x4 hv = *(const u32x4*)&h0[base + i * 8];
      u32x4 o;
#pragma unroll
      for (int j = 0; j < 4; ++j) {
        float a = fmaxf(bflo(zv[j]) + bflo(hv[j]), 0.f);
        float b = fmaxf(bfhi(zv[j]) + bfhi(hv[j]), 0.f);
        o[j] = (unsigned int)f2bf(a) | ((unsigned int)f2bf(b) << 16);
      }
      *(u32x4*)&hout[base + i * 8] = o;
    }
  }
}

// ---------------- Pooling ----------------
__global__ void k_starts(const int* __restrict__ batch, int* __restrict__ starts) {
  int n = blockIdx.x * 256 + threadIdx.x;
  if (n >= N_NODES) return;
  int b = batch[n];
  if (n == 0) {
    for (int g = 0; g <= b; ++g) starts[g] = 0;
  } else {
    int bp = batch[n - 1];
    for (int g = bp + 1; g <= b; ++g) starts[g] = n;
  }
  if (n == N_NODES - 1) {
    for (int g = b + 1; g <= N_GRAPHS; ++g) starts[g] = N_NODES;
  }
}

__global__ __launch_bounds__(256) void k_pool(const unsigned short* __restrict__ h, const int* __restrict__ starts,
                                              const float* __restrict__ Wf, const float* __restrict__ bf_,
                                              float* __restrict__ out) {
  __shared__ float r[4];
  int g = blockIdx.x, tid = threadIdx.x;
  int lane = tid & 63, w = tid >> 6;
  int beg = starts[g], end = starts[g + 1];
  const unsigned int* hu = (const unsigned int*)h;
  float sx = 0.f, sy = 0.f;
  for (int n = beg + w; n < end; n += 4) {
    unsigned int v = hu[(size_t)n * 64 + lane];
    sx += bflo(v);
    sy += bfhi(v);
  }
  float val = sx * Wf[2 * lane] + sy * Wf[2 * lane + 1];
#pragma unroll
  for (int off = 32; off > 0; off >>= 1) val += __shfl_down(val, off);
  if (lane == 0) r[w] = val;
  __syncthreads();
  if (tid == 0) out[g] = r[0] + r[1] + r[2] + r[3] + bf_[0];
}

extern "C" void kernel_launch(void* const* d_in, const int* in_sizes, int n_in,
                              void* d_out, int out_size, void* d_ws, size_t ws_size,
                              hipStream_t stream) {
  const float* x = (const float*)d_in[0];
  const int* ei = (const int*)d_in[1];
  const int* srcv = ei;
  const int* dstv = ei + N_EDGES;
  const int* batch = (const int*)d_in[3];
  const float* W0 = (const float*)d_in[4];
  const float* b0 = (const float*)d_in[5];
  const float* W1 = (const float*)d_in[6];
  const float* b1 = (const float*)d_in[7];
  const float* W2 = (const float*)d_in[8];
  const float* b2 = (const float*)d_in[9];
  const float* Wf = (const float*)d_in[10];
  const float* bf_ = (const float*)d_in[11];
  float* out = (float*)d_out;

  char* ws = (char*)d_ws;
  size_t o = 0;
  auto alloc = [&](size_t bytes) {
    size_t r = o;
    o = (o + bytes + 255) & ~(size_t)255;
    return r;
  };
  int* offs = (int*)(ws + alloc((N_NODES + 1) * sizeof(int)));
  int* gcnt = (int*)(ws + alloc(NB * sizeof(int)));
  int* boff = (int*)(ws + alloc((NB + 1) * sizeof(int)));
  unsigned int* ebuf = (unsigned int*)(ws + alloc((size_t)NB * BCAP * 4));
  int* csr = (int*)(ws + alloc((size_t)N_EDGES * sizeof(int)));
  int* starts = (int*)(ws + alloc((N_GRAPHS + 1) * sizeof(int)));
  // +1 zero-pad row at index N_NODES (gather target for out-of-range edge slots)
  unsigned short* h0 = (unsigned short*)(ws + alloc((size_t)(N_NODES + 1) * H * 2));
  unsigned short* hA = (unsigned short*)(ws + alloc((size_t)(N_NODES + 1) * H * 2));
  unsigned short* hB = (unsigned short*)(ws + alloc((size_t)(N_NODES + 1) * H * 2));
  unsigned short* wbuf = (unsigned short*)(ws + alloc((size_t)9 * WSLOT * 2));

  (void)hipMemsetAsync(gcnt, 0, NB * sizeof(int), stream);
  (void)hipMemsetAsync(h0 + (size_t)N_NODES * H, 0, H * 2, stream);
  (void)hipMemsetAsync(hA + (size_t)N_NODES * H, 0, H * 2, stream);
  (void)hipMemsetAsync(hB + (size_t)N_NODES * H, 0, H * 2, stream);
  k_wprep<<<72, 256, 0, stream>>>(W0, W1, W2, wbuf);
  k_bucket<<<NB, 256, 0, stream>>>(srcv, dstv, gcnt, ebuf);
  k_bscan<<<1, 512, 0, stream>>>(gcnt, boff);
  k_bsort<<<NB, 256, 0, stream>>>(ebuf, gcnt, boff, csr, offs);
  k_starts<<<(N_NODES + 255) / 256, 256, 0, stream>>>(batch, starts);

  const int nblk = (N_NODES + 127) / 128;
  k_lin<<<nblk, 512, 0, stream>>>(x, wbuf, b0, h0);
  for (int i = 0; i < DEPTH; ++i) {
    const unsigned short* hin = (i == 0) ? h0 : ((i & 1) ? hA : hB);
    unsigned short* hout = (i & 1) ? hB : hA;
    k_mlp<<<nblk, 512, 0, stream>>>(hin, offs, csr,
                                    wbuf + (size_t)(1 + i) * WSLOT, b1 + (size_t)i * H,
                                    wbuf + (size_t)(1 + DEPTH + i) * WSLOT, b2 + (size_t)i * H,
                                    h0, hout);
  }
  k_pool<<<N_GRAPHS, 256, 0, stream>>>(hB, starts, Wf, bf_, out);
}